// Round 5
// baseline (36.772 us; speedup 1.0000x reference)
//
#include <hip/hip_runtime.h>
#include <math.h>

// Problem constants (match reference setup_inputs)
#define NB 8
#define NC 64
#define NL 65536
#define LOUT (NL / 2)          // stride-2 downsample -> 32768
#define OPT 8                  // outputs per thread (owns 16 inputs + 4+4 halo = 24 loaded)
#define TPB 256

typedef float f32x4 __attribute__((ext_vector_type(4)));  // native vec: OK for nontemporal builtins

// out[b,c,j] = max(0, max_{d=-3..3} f[b,c, 2j+d] - d^2/(4*t_c)),  OOB -> -inf
__global__ __launch_bounds__(TPB) void parabolic_pool1d_kernel(
    const float* __restrict__ f,
    const float* __restrict__ t,
    float* __restrict__ out)
{
    const int THREADS_PER_ROW = LOUT / OPT;             // 4096
    long long gid = (long long)blockIdx.x * blockDim.x + threadIdx.x;
    int row = (int)(gid / THREADS_PER_ROW);             // b*NC + c
    int tr  = (int)(gid - (long long)row * THREADS_PER_ROW);
    if (row >= NB * NC) return;

    const int c = row & (NC - 1);
    const float t4 = 4.0f * t[c];
    const float c1 = -1.0f / t4;
    const float c2 = -4.0f / t4;
    const float c3 = -9.0f / t4;

    const float* __restrict__ frow = f + (long long)row * NL;
    const int base = tr * (2 * OPT);                    // first center = base

    // v[k] = f[base - 4 + k], k = 0..23  (centers at v[4],v[6],...,v[18]; max tap v[21])
    float v[24];
    if (tr > 0 && tr < THREADS_PER_ROW - 1) {
        // fully interior: 6 aligned CACHED float4 loads (halo overlap absorbed by L1/L2;
        // NT loads here cost +55% — measured R3)
        const float4* p = (const float4*)(frow + base - 4);
        #pragma unroll
        for (int q = 0; q < 6; ++q) {
            float4 a = p[q];
            v[4*q + 0] = a.x; v[4*q + 1] = a.y; v[4*q + 2] = a.z; v[4*q + 3] = a.w;
        }
    } else {
        #pragma unroll
        for (int k = 0; k < 24; ++k) {
            int idx = base - 4 + k;
            v[k] = (idx >= 0 && idx < NL) ? frow[idx] : -INFINITY;
        }
    }

    float o[OPT];
    #pragma unroll
    for (int j = 0; j < OPT; ++j) {
        const int m = 2 * j + 4;                        // center index in v
        float m0 = v[m];
        float m1 = fmaxf(v[m - 1], v[m + 1]) + c1;
        float m2 = fmaxf(v[m - 2], v[m + 2]) + c2;
        float m3 = fmaxf(v[m - 3], v[m + 3]) + c3;
        float r  = fmaxf(fmaxf(m0, m1), fmaxf(m2, m3));
        o[j] = fmaxf(r, 0.0f);
    }

    // store stream is write-once, never re-read: NT stores (loads stay cached)
    f32x4* outp = (f32x4*)(out + (long long)row * LOUT + tr * OPT);
    f32x4 o0 = { o[0], o[1], o[2], o[3] };
    f32x4 o1 = { o[4], o[5], o[6], o[7] };
    __builtin_nontemporal_store(o0, outp + 0);
    __builtin_nontemporal_store(o1, outp + 1);
}

extern "C" void kernel_launch(void* const* d_in, const int* in_sizes, int n_in,
                              void* d_out, int out_size, void* d_ws, size_t ws_size,
                              hipStream_t stream) {
    const float* f = (const float*)d_in[0];
    const float* t = (const float*)d_in[1];
    float* out = (float*)d_out;

    const long long total_threads = (long long)NB * NC * (LOUT / OPT);
    const int blocks = (int)((total_threads + TPB - 1) / TPB);   // 8192
    parabolic_pool1d_kernel<<<blocks, TPB, 0, stream>>>(f, t, out);
}

// Round 6
// 33.636 us; speedup vs baseline: 1.0932x; 1.0932x over previous
//
#include <hip/hip_runtime.h>
#include <math.h>

// Problem constants (match reference setup_inputs)
#define NB 8
#define NC 64
#define NL 65536
#define LOUT (NL / 2)          // stride-2 downsample -> 32768
#define OUT_PER_THREAD 4       // outputs per thread; OPT=8 measured WORSE (36.8 vs 33.9 us, R5)
#define TPB 256

typedef float f32x4 __attribute__((ext_vector_type(4)));  // native vec: OK for nontemporal builtins

// out[b,c,j] = max(0, max_{d=-3..3} f[b,c, 2j+d] - d^2/(4*t_c)),  OOB -> -inf
__global__ __launch_bounds__(TPB) void parabolic_pool1d_kernel(
    const float* __restrict__ f,
    const float* __restrict__ t,
    float* __restrict__ out)
{
    const int THREADS_PER_ROW = LOUT / OUT_PER_THREAD;  // 8192
    long long gid = (long long)blockIdx.x * blockDim.x + threadIdx.x;
    int row = (int)(gid / THREADS_PER_ROW);             // b*NC + c
    int tr  = (int)(gid - (long long)row * THREADS_PER_ROW);
    if (row >= NB * NC) return;

    const int c = row & (NC - 1);
    const float t4 = 4.0f * t[c];
    const float c1 = -1.0f / t4;
    const float c2 = -4.0f / t4;
    const float c3 = -9.0f / t4;

    const float* __restrict__ frow = f + (long long)row * NL;
    const int base = tr * (2 * OUT_PER_THREAD);         // first center = base

    // v[k] = f[base - 4 + k], k = 0..15  (centers at v[4],v[6],v[8],v[10])
    float v[16];
    if (tr > 0 && tr < THREADS_PER_ROW - 1) {
        // fully interior: 4 aligned CACHED float4 loads (halo overlap absorbed by L1/L2;
        // NT loads here cost +55% — measured R3)
        const float4* p = (const float4*)(frow + base - 4);
        float4 a = p[0], b = p[1], cq = p[2], d = p[3];
        v[0]=a.x;  v[1]=a.y;  v[2]=a.z;  v[3]=a.w;
        v[4]=b.x;  v[5]=b.y;  v[6]=b.z;  v[7]=b.w;
        v[8]=cq.x; v[9]=cq.y; v[10]=cq.z; v[11]=cq.w;
        v[12]=d.x; v[13]=d.y; v[14]=d.z; v[15]=d.w;
    } else {
        #pragma unroll
        for (int k = 0; k < 16; ++k) {
            int idx = base - 4 + k;
            v[k] = (idx >= 0 && idx < NL) ? frow[idx] : -INFINITY;
        }
    }

    f32x4 o;
    #pragma unroll
    for (int j = 0; j < OUT_PER_THREAD; ++j) {
        const int m = 2 * j + 4;                        // center index in v
        float m0 = v[m];
        float m1 = fmaxf(v[m - 1], v[m + 1]) + c1;
        float m2 = fmaxf(v[m - 2], v[m + 2]) + c2;
        float m3 = fmaxf(v[m - 3], v[m + 3]) + c3;
        float r  = fmaxf(fmaxf(m0, m1), fmaxf(m2, m3));
        o[j] = fmaxf(r, 0.0f);
    }

    // store stream is write-once, never re-read: NT store only (loads stay cached)
    f32x4* outp = (f32x4*)(out + (long long)row * LOUT + tr * OUT_PER_THREAD);
    __builtin_nontemporal_store(o, outp);
}

extern "C" void kernel_launch(void* const* d_in, const int* in_sizes, int n_in,
                              void* d_out, int out_size, void* d_ws, size_t ws_size,
                              hipStream_t stream) {
    const float* f = (const float*)d_in[0];
    const float* t = (const float*)d_in[1];
    float* out = (float*)d_out;

    const long long total_threads = (long long)NB * NC * (LOUT / OUT_PER_THREAD);
    const int blocks = (int)((total_threads + TPB - 1) / TPB);   // 16384
    parabolic_pool1d_kernel<<<blocks, TPB, 0, stream>>>(f, t, out);
}